// Round 1
// baseline (837.365 us; speedup 1.0000x reference)
//
#include <hip/hip_runtime.h>
#include <math.h>

#define HID 128
#define DHD 32
#define N_T 90

__device__ __forceinline__ float gelu_f(float x) {
    return 0.5f * x * (1.0f + erff(x * 0.70710678118654752f));
}
__device__ __forceinline__ float softplus_f(float x) {
    return fmaxf(x, 0.0f) + log1pf(expf(-fabsf(x)));
}

// ---------------- signature features ----------------
// Lead-lag path increments alternate: even substep dx=(d0,d1,0,0) [P=0],
// odd substep dx=(0,0,d0,d1) [P=2], with (d0,d1)=x[i+1]-x[i].
template<int P>
__device__ __forceinline__ void sig_substep(float c1[4], float c2[16], float s3[64],
                                            float d0, float d1) {
    float h00 = 0.5f * d0 * d0, h01 = 0.5f * d0 * d1, h11 = 0.5f * d1 * d1;
    // s3 += c2_old (x) dx
#pragma unroll
    for (int a = 0; a < 4; ++a) {
#pragma unroll
        for (int b = 0; b < 4; ++b) {
            float c2ab = c2[a * 4 + b];
            s3[a * 16 + b * 4 + P + 0] += c2ab * d0;
            s3[a * 16 + b * 4 + P + 1] += c2ab * d1;
        }
    }
    // s3 += 0.5 * c1_old (x) dx (x) dx
#pragma unroll
    for (int a = 0; a < 4; ++a) {
        float c = c1[a];
        s3[a * 16 + (P + 0) * 4 + (P + 0)] += c * h00;
        s3[a * 16 + (P + 0) * 4 + (P + 1)] += c * h01;
        s3[a * 16 + (P + 1) * 4 + (P + 0)] += c * h01;
        s3[a * 16 + (P + 1) * 4 + (P + 1)] += c * h11;
    }
    // s3 += dx (x) dx (x) dx / 6
    const float i6 = 0.16666666666666666f;
    float t000 = d0 * d0 * d0 * i6, t001 = d0 * d0 * d1 * i6;
    float t011 = d0 * d1 * d1 * i6, t111 = d1 * d1 * d1 * i6;
    s3[(P + 0) * 16 + (P + 0) * 4 + (P + 0)] += t000;
    s3[(P + 0) * 16 + (P + 0) * 4 + (P + 1)] += t001;
    s3[(P + 0) * 16 + (P + 1) * 4 + (P + 0)] += t001;
    s3[(P + 0) * 16 + (P + 1) * 4 + (P + 1)] += t011;
    s3[(P + 1) * 16 + (P + 0) * 4 + (P + 0)] += t001;
    s3[(P + 1) * 16 + (P + 0) * 4 + (P + 1)] += t011;
    s3[(P + 1) * 16 + (P + 1) * 4 + (P + 0)] += t011;
    s3[(P + 1) * 16 + (P + 1) * 4 + (P + 1)] += t111;
    // c2 += c1_old (x) dx + 0.5 dx (x) dx
#pragma unroll
    for (int a = 0; a < 4; ++a) {
        float c = c1[a];
        c2[a * 4 + P + 0] += c * d0;
        c2[a * 4 + P + 1] += c * d1;
    }
    c2[(P + 0) * 4 + (P + 0)] += h00;
    c2[(P + 0) * 4 + (P + 1)] += h01;
    c2[(P + 1) * 4 + (P + 0)] += h01;
    c2[(P + 1) * 4 + (P + 1)] += h11;
    // c1 += dx
    c1[P + 0] += d0;
    c1[P + 1] += d1;
}

__global__ void sig_kernel(const float* __restrict__ nf, float* __restrict__ X, int nn) {
    int node = blockIdx.x * blockDim.x + threadIdx.x;
    int win = blockIdx.y;            // 0,1,2 -> w = 7,28,90 (uniform per block)
    if (node >= nn) return;
    int w = (win == 0) ? 7 : (win == 1) ? 28 : 90;
    const float* xp = nf + (size_t)node * (N_T * 2) + (size_t)(N_T - w) * 2;
    float c1[4] = {0.f, 0.f, 0.f, 0.f};
    float c2[16] = {0.f};
    float s3[64] = {0.f};
    float p0 = xp[0], p1 = xp[1];
    for (int i = 1; i < w; ++i) {
        float n0 = xp[i * 2], n1 = xp[i * 2 + 1];
        float d0 = n0 - p0, d1 = n1 - p1;
        sig_substep<0>(c1, c2, s3, d0, d1);   // lead step
        sig_substep<2>(c1, c2, s3, d0, d1);   // lag step
        p0 = n0; p1 = n1;
    }
    float* o = X + (size_t)node * 292 + win * 84;
#pragma unroll
    for (int k = 0; k < 4; ++k) o[k] = c1[k];
#pragma unroll
    for (int k = 0; k < 16; ++k) o[4 + k] = c2[k];
#pragma unroll
    for (int k = 0; k < 64; ++k) o[20 + k] = s3[k];
}

// ---------------- embeddings -> X[:, 252:292] ----------------
__global__ void emb_kernel(float* __restrict__ X,
                           const int* __restrict__ store_id, const int* __restrict__ dept_id,
                           const int* __restrict__ cat_id, const int* __restrict__ state_id,
                           const int* __restrict__ item_id,
                           const float* __restrict__ e_store, const float* __restrict__ e_dept,
                           const float* __restrict__ e_cat, const float* __restrict__ e_state,
                           const float* __restrict__ e_item, int nn) {
    int n = blockIdx.x * blockDim.x + threadIdx.x;
    if (n >= nn) return;
    float* o = X + (size_t)n * 292 + 252;
    const float* p;
    p = e_store + store_id[n] * 8;
#pragma unroll
    for (int j = 0; j < 8; ++j) o[j] = p[j];
    p = e_dept + dept_id[n] * 8;
#pragma unroll
    for (int j = 0; j < 8; ++j) o[8 + j] = p[j];
    p = e_cat + cat_id[n] * 4;
#pragma unroll
    for (int j = 0; j < 4; ++j) o[16 + j] = p[j];
    p = e_state + state_id[n] * 4;
#pragma unroll
    for (int j = 0; j < 4; ++j) o[20 + j] = p[j];
    p = e_item + item_id[n] * 16;
#pragma unroll
    for (int j = 0; j < 16; ++j) o[24 + j] = p[j];
}

// ---------------- generic f32 GEMM: C = act(A@B + bias) ----------------
// A: MxK row-major, B: KxN row-major. BM=BN=64, BK=16, 4x4 per thread.
__global__ __launch_bounds__(256)
void gemm_kernel(const float* __restrict__ A, const float* __restrict__ B,
                 const float* __restrict__ bias, float* __restrict__ C,
                 int M, int N, int K, int act) {
    __shared__ float As[16][68];   // [k][m], padded
    __shared__ float Bs[16][68];   // [k][n], padded
    int tid = threadIdx.x;
    int bm = blockIdx.x * 64;
    int bn = blockIdx.y * 64;
    int tx = tid & 15, ty = tid >> 4;
    int ar = tid >> 2, ac = (tid & 3) * 4;   // A load: row ar, cols ac..ac+3
    int br = tid >> 4, bc = (tid & 15) * 4;  // B load: row br, cols bc..bc+3
    float acc[4][4] = {};
    for (int k0 = 0; k0 < K; k0 += 16) {
        float av[4] = {0.f, 0.f, 0.f, 0.f};
        int grow = bm + ar;
        if (grow < M) {
            int gc = k0 + ac;
            if (gc + 4 <= K) {
                const float4 v = *(const float4*)(A + (size_t)grow * K + gc);
                av[0] = v.x; av[1] = v.y; av[2] = v.z; av[3] = v.w;
            } else {
                for (int u = 0; u < 4; ++u)
                    if (gc + u < K) av[u] = A[(size_t)grow * K + gc + u];
            }
        }
        float bv[4] = {0.f, 0.f, 0.f, 0.f};
        int brow = k0 + br;
        if (brow < K) {
            int gc = bn + bc;
            if (gc + 4 <= N) {
                const float4 v = *(const float4*)(B + (size_t)brow * N + gc);
                bv[0] = v.x; bv[1] = v.y; bv[2] = v.z; bv[3] = v.w;
            } else {
                for (int u = 0; u < 4; ++u)
                    if (gc + u < N) bv[u] = B[(size_t)brow * N + gc + u];
            }
        }
        __syncthreads();
        As[ac + 0][ar] = av[0];
        As[ac + 1][ar] = av[1];
        As[ac + 2][ar] = av[2];
        As[ac + 3][ar] = av[3];
        *(float4*)&Bs[br][bc] = make_float4(bv[0], bv[1], bv[2], bv[3]);
        __syncthreads();
#pragma unroll
        for (int kk = 0; kk < 16; ++kk) {
            float4 a = *(const float4*)&As[kk][ty * 4];
            float4 b = *(const float4*)&Bs[kk][tx * 4];
            float aa[4] = {a.x, a.y, a.z, a.w};
            float bb[4] = {b.x, b.y, b.z, b.w};
#pragma unroll
            for (int i = 0; i < 4; ++i)
#pragma unroll
                for (int j = 0; j < 4; ++j) acc[i][j] += aa[i] * bb[j];
        }
    }
#pragma unroll
    for (int i = 0; i < 4; ++i) {
        int row = bm + ty * 4 + i;
        if (row >= M) continue;
        int col0 = bn + tx * 4;
        float v[4];
#pragma unroll
        for (int j = 0; j < 4; ++j) {
            float x = acc[i][j];
            int col = col0 + j;
            if (col < N && bias) x += bias[col];
            if (act == 1) x = gelu_f(x);
            v[j] = x;
        }
        if (col0 + 4 <= N) {
            *(float4*)(C + (size_t)row * N + col0) = make_float4(v[0], v[1], v[2], v[3]);
        } else {
            for (int j = 0; j < 4; ++j)
                if (col0 + j < N) C[(size_t)row * N + col0 + j] = v[j];
        }
    }
}

// ---------------- fused gelu + layernorm (in-place, 128 cols) ----------------
__global__ void gelu_ln_kernel(float* __restrict__ h, const float* __restrict__ g,
                               const float* __restrict__ b) {
    int row = blockIdx.x, t = threadIdx.x;
    float* hp = h + (size_t)row * HID;
    float x = gelu_f(hp[t]);
    __shared__ float red[2];
    float s = x;
#pragma unroll
    for (int off = 32; off > 0; off >>= 1) s += __shfl_xor(s, off);
    if ((t & 63) == 0) red[t >> 6] = s;
    __syncthreads();
    float mean = (red[0] + red[1]) * (1.0f / 128.0f);
    float d = x - mean;
    float vs = d * d;
    __syncthreads();
#pragma unroll
    for (int off = 32; off > 0; off >>= 1) vs += __shfl_xor(vs, off);
    if ((t & 63) == 0) red[t >> 6] = vs;
    __syncthreads();
    float var = (red[0] + red[1]) * (1.0f / 128.0f);
    hp[t] = d / sqrtf(var + 1e-5f) * g[t] + b[t];
}

// ---------------- CSR build (dst-indexed) ----------------
__global__ void hist_kernel(const int* __restrict__ dst, int* __restrict__ deg, int e) {
    int i = blockIdx.x * blockDim.x + threadIdx.x;
    if (i < e) atomicAdd(&deg[dst[i]], 1);
}

__global__ void scan_kernel(const int* __restrict__ deg, int* __restrict__ row_start,
                            int* __restrict__ cursor, int n) {
    __shared__ int wsum[16];
    __shared__ int chunk_total;
    int t = threadIdx.x;
    int lane = t & 63, wv = t >> 6;
    int carry = 0;
    for (int base = 0; base < n; base += 1024) {
        int i = base + t;
        int d = (i < n) ? deg[i] : 0;
        int v = d;
#pragma unroll
        for (int off = 1; off < 64; off <<= 1) {
            int u = __shfl_up(v, off);
            if (lane >= off) v += u;
        }
        if (lane == 63) wsum[wv] = v;
        __syncthreads();
        if (t == 0) {
            int acc2 = 0;
#pragma unroll
            for (int k = 0; k < 16; ++k) {
                int tmp = wsum[k];
                wsum[k] = acc2;
                acc2 += tmp;
            }
            chunk_total = acc2;
        }
        __syncthreads();
        int excl = v - d + wsum[wv] + carry;
        if (i < n) {
            row_start[i] = excl;
            cursor[i] = excl;
        }
        carry += chunk_total;
        __syncthreads();
    }
    if (t == 0) row_start[n] = carry;
}

__global__ void scatter_kernel(const int* __restrict__ src, const int* __restrict__ dst,
                               const int* __restrict__ et, int* __restrict__ cursor,
                               int* __restrict__ csr, int e) {
    int i = blockIdx.x * blockDim.x + threadIdx.x;
    if (i < e) {
        int d = dst[i];
        int pos = atomicAdd(&cursor[d], 1);
        csr[pos] = src[i] | (et[i] << 20);   // src < 2^20, et in {0,1,2}
    }
}

// ---------------- per-(node,head) attention dots ----------------
__global__ void esed_kernel(const float* __restrict__ q, const float* __restrict__ asrc,
                            const float* __restrict__ adst, float* __restrict__ es,
                            float* __restrict__ ed, int nn) {
    int idx = blockIdx.x * blockDim.x + threadIdx.x;
    if (idx >= nn * 4) return;
    int n = idx >> 2, hh = idx & 3;
    const float* qp = q + (size_t)n * HID + hh * DHD;
    const float* ap = asrc + hh * DHD;
    const float* dp = adst + hh * DHD;
    float s = 0.f, d = 0.f;
#pragma unroll
    for (int k = 0; k < DHD; ++k) {
        float qv = qp[k];
        s += qv * ap[k];
        d += qv * dp[k];
    }
    es[idx] = s;
    ed[idx] = d;
}

// ---------------- GAT aggregation: online softmax + fused elu(msg + r) ----------------
__global__ void gat_agg_kernel(const float* __restrict__ q, const float* __restrict__ r,
                               const float* __restrict__ es, const float* __restrict__ ed,
                               const float* __restrict__ etb,
                               const int* __restrict__ row_start, const int* __restrict__ csr,
                               float* __restrict__ hout, int nn) {
    int n = blockIdx.x;
    int t = threadIdx.x;   // 0..127 : head = t>>5, dim = t&31
    int hh = t >> 5;
    float b0 = etb[0 * 4 + hh], b1 = etb[1 * 4 + hh], b2 = etb[2 * 4 + hh];
    float edn = ed[n * 4 + hh];
    int e0 = row_start[n], e1 = row_start[n + 1];
    float m = -INFINITY, den = 0.f, acc = 0.f;
    for (int e = e0; e < e1; ++e) {
        int info = csr[e];
        int s = info & 0xFFFFF;
        int et = info >> 20;
        float lg = es[s * 4 + hh] + edn + (et == 0 ? b0 : (et == 1 ? b1 : b2));
        lg = lg > 0.f ? lg : 0.2f * lg;            // leaky_relu(0.2)
        float qv = q[(size_t)s * HID + t];
        float nm = fmaxf(m, lg);
        float corr = expf(m - nm);                 // exp(-inf)=0 on first edge
        float p = expf(lg - nm);
        den = den * corr + p;
        acc = acc * corr + p * qv;
        m = nm;
    }
    float msg = acc / (den + 1e-9f);
    float v = msg + r[(size_t)n * HID + t];
    hout[(size_t)n * HID + t] = v > 0.f ? v : expm1f(v);   // elu
}

// ---------------- final scaling + clip ----------------
__global__ void final_kernel(const float* __restrict__ y, const float* __restrict__ hs,
                             const float* __restrict__ gs, const int* __restrict__ dept_ids,
                             const float* __restrict__ hm, float* __restrict__ out, int nn) {
    int idx = blockIdx.x * blockDim.x + threadIdx.x;
    if (idx >= nn * 28) return;
    int n = idx / 28, j = idx - n * 28;
    float v = y[idx] * softplus_f(hs[j]) * softplus_f(gs[dept_ids[n]]);
    float hi = 20.0f * hm[n];
    out[idx] = fminf(fmaxf(v, 0.0f), hi);
}

extern "C" void kernel_launch(void* const* d_in, const int* in_sizes, int n_in,
                              void* d_out, int out_size, void* d_ws, size_t ws_size,
                              hipStream_t stream) {
    const float* nf       = (const float*)d_in[0];
    const int*   eidx     = (const int*)d_in[1];
    const int*   etype    = (const int*)d_in[2];
    const int*   store_id = (const int*)d_in[3];
    const int*   dept_id  = (const int*)d_in[4];
    const int*   cat_id   = (const int*)d_in[5];
    const int*   state_id = (const int*)d_in[6];
    const int*   item_id  = (const int*)d_in[7];
    const int*   dept_ids = (const int*)d_in[8];
    const float* hm       = (const float*)d_in[9];
    const float* e_store  = (const float*)d_in[10];
    const float* e_dept   = (const float*)d_in[11];
    const float* e_cat    = (const float*)d_in[12];
    const float* e_state  = (const float*)d_in[13];
    const float* e_item   = (const float*)d_in[14];
    const float* fusion_W = (const float*)d_in[15];
    const float* fusion_b = (const float*)d_in[16];
    const float* ln_g     = (const float*)d_in[17];
    const float* ln_b     = (const float*)d_in[18];
    const float* gat_W    = (const float*)d_in[19];
    const float* gat_b    = (const float*)d_in[20];
    const float* gat_asrc = (const float*)d_in[21];
    const float* gat_adst = (const float*)d_in[22];
    const float* gat_et   = (const float*)d_in[23];
    const float* gat_Wres = (const float*)d_in[24];
    const float* pW1      = (const float*)d_in[25];
    const float* pb1      = (const float*)d_in[26];
    const float* pW2      = (const float*)d_in[27];
    const float* pb2      = (const float*)d_in[28];
    const float* pW3      = (const float*)d_in[29];
    const float* pb3      = (const float*)d_in[30];
    const float* hs       = (const float*)d_in[31];
    const float* gs       = (const float*)d_in[32];

    const int nn = in_sizes[3];   // 30490 nodes
    const int ee = in_sizes[2];   // 487840 edges
    const int* src = eidx;
    const int* dst = eidx + ee;

    // workspace layout (floats then ints), ~117 MB total
    float* ws = (float*)d_ws;
    float* X  = ws;                              // nn x 292
    float* h  = X + (size_t)nn * 292;            // nn x 128
    float* q  = h + (size_t)nn * 128;            // nn x 128
    float* r  = q + (size_t)nn * 128;            // nn x 128
    float* t2 = r + (size_t)nn * 128;            // nn x 256
    float* es = t2 + (size_t)nn * 256;           // nn x 4
    float* ed = es + (size_t)nn * 4;             // nn x 4
    int* deg       = (int*)(ed + (size_t)nn * 4); // nn
    int* row_start = deg + nn;                    // nn+1
    int* cursor    = row_start + nn + 1;          // nn
    int* csr       = cursor + nn;                 // ee
    float* t1 = X;                                // reuse (nn x 256 <= nn x 292)
    float* y  = q;                                // reuse (nn x 28 <= nn x 128)

    // --- CSR build ---
    hipMemsetAsync(deg, 0, nn * sizeof(int), stream);
    hist_kernel<<<(ee + 255) / 256, 256, 0, stream>>>(dst, deg, ee);
    scan_kernel<<<1, 1024, 0, stream>>>(deg, row_start, cursor, nn);
    scatter_kernel<<<(ee + 255) / 256, 256, 0, stream>>>(src, dst, etype, cursor, csr, ee);

    // --- features ---
    dim3 sg((nn + 255) / 256, 3);
    sig_kernel<<<sg, 256, 0, stream>>>(nf, X, nn);
    emb_kernel<<<(nn + 255) / 256, 256, 0, stream>>>(X, store_id, dept_id, cat_id, state_id,
                                                     item_id, e_store, e_dept, e_cat, e_state,
                                                     e_item, nn);

    // --- fusion + LN ---
    dim3 g1((nn + 63) / 64, 2);
    gemm_kernel<<<g1, 256, 0, stream>>>(X, fusion_W, fusion_b, h, nn, 128, 292, 0);
    gelu_ln_kernel<<<nn, 128, 0, stream>>>(h, ln_g, ln_b);

    // --- 3 GAT layers ---
    for (int l = 0; l < 3; ++l) {
        gemm_kernel<<<g1, 256, 0, stream>>>(h, gat_W + (size_t)l * 128 * 128,
                                            gat_b + l * 128, q, nn, 128, 128, 0);
        gemm_kernel<<<g1, 256, 0, stream>>>(h, gat_Wres + (size_t)l * 128 * 128,
                                            nullptr, r, nn, 128, 128, 0);
        esed_kernel<<<(nn * 4 + 255) / 256, 256, 0, stream>>>(q, gat_asrc + l * 128,
                                                              gat_adst + l * 128, es, ed, nn);
        gat_agg_kernel<<<nn, 128, 0, stream>>>(q, r, es, ed, gat_et + l * 12,
                                               row_start, csr, h, nn);
    }

    // --- prediction MLP ---
    dim3 g2((nn + 63) / 64, 4);
    gemm_kernel<<<g2, 256, 0, stream>>>(h, pW1, pb1, t1, nn, 256, 128, 1);
    gemm_kernel<<<g2, 256, 0, stream>>>(t1, pW2, pb2, t2, nn, 256, 256, 1);
    dim3 g3((nn + 63) / 64, 1);
    gemm_kernel<<<g3, 256, 0, stream>>>(t2, pW3, pb3, y, nn, 28, 256, 0);
    final_kernel<<<(nn * 28 + 255) / 256, 256, 0, stream>>>(y, hs, gs, dept_ids, hm,
                                                            (float*)d_out, nn);
}